// Round 12
// baseline (550.788 us; speedup 1.0000x reference)
//
#include <hip/hip_runtime.h>

#define B_    8
#define D_IN  256
#define D_HID 1024
#define D_OUT 40000       // = 200*200
#define HW4   10000       // D_OUT/4
#define CHW4  2560000     // 256*200*200/4
#define TOT4  20480000    // 8*CHW4
#define NBLK  1250        // 1250*256 = 320000 = 32*HW4 -> P4 p-invariance
#define NTHR  256
#define KS    8
#define CHUNK (D_HID / KS)       // 128
#define NUNITS (157 * KS)        // 1256 P2 wave-units
#define GSZ   (NBLK * NTHR)      // 320000
                                  // TOT4/GSZ = 64 iters, CHW4/GSZ = 8

typedef float f32x4 __attribute__((ext_vector_type(4)));
typedef unsigned long long u64;

// agent-scope 16B store (2x64b atomics): visible at coherence point (R8-proven)
__device__ __forceinline__ void store16_agent(f32x4 v, f32x4* p) {
    union { f32x4 v; u64 q[2]; } u; u.v = v;
    u64* d = (u64*)p;
    __hip_atomic_store(d,     u.q[0], __ATOMIC_RELAXED, __HIP_MEMORY_SCOPE_AGENT);
    __hip_atomic_store(d + 1, u.q[1], __ATOMIC_RELAXED, __HIP_MEMORY_SCOPE_AGENT);
}

// Flag-array grid barrier: per-block release store to its own word (parallel),
// block 0 polls all flags then publishes gen; others spin on gen. No RMW chain.
__device__ __forceinline__ void grid_barrier(unsigned* flags, unsigned* gen, unsigned g) {
    __builtin_amdgcn_fence(__ATOMIC_RELEASE, "agent");   // order each thread's writes
    __syncthreads();
    if (blockIdx.x == 0) {
        if (threadIdx.x == 0)
            __hip_atomic_store(&flags[0], g, __ATOMIC_RELEASE, __HIP_MEMORY_SCOPE_AGENT);
        #pragma unroll
        for (int j = 0; j < 5; ++j) {
            int idx = threadIdx.x + j * NTHR;
            if (idx < NBLK) {
                while (__hip_atomic_load(&flags[idx], __ATOMIC_RELAXED,
                                         __HIP_MEMORY_SCOPE_AGENT) < g)
                    __builtin_amdgcn_s_sleep(2);
            }
        }
        __syncthreads();
        __builtin_amdgcn_fence(__ATOMIC_ACQUIRE, "agent");
        if (threadIdx.x == 0)
            __hip_atomic_store(gen, g, __ATOMIC_RELEASE, __HIP_MEMORY_SCOPE_AGENT);
    } else {
        if (threadIdx.x == 0) {
            __hip_atomic_store(&flags[blockIdx.x], g, __ATOMIC_RELEASE,
                               __HIP_MEMORY_SCOPE_AGENT);
            while (__hip_atomic_load(gen, __ATOMIC_RELAXED,
                                     __HIP_MEMORY_SCOPE_AGENT) < g)
                __builtin_amdgcn_s_sleep(8);
        }
        __syncthreads();
        __builtin_amdgcn_fence(__ATOMIC_ACQUIRE, "agent");
    }
}

__global__ __launch_bounds__(NTHR, 5)   // 5 blk/CU guaranteed -> 1280 >= 1250 co-resident
void fused_kernel(const float* __restrict__ x,
                  const float* __restrict__ loc,
                  const float* __restrict__ W1,
                  const float* __restrict__ b1,
                  const float* __restrict__ W2,
                  const float* __restrict__ b2,
                  float* __restrict__ out,
                  unsigned* __restrict__ gen,
                  unsigned* __restrict__ flags,
                  float* __restrict__ hT,
                  float* __restrict__ partial,
                  float* __restrict__ wmap) {
    __shared__ float red[NTHR];
    const int bid  = blockIdx.x;
    const int tid  = threadIdx.x;
    const int wid  = tid >> 6;
    const int lane = tid & 63;

    // ---------- P1: hT = leakyrelu(loc @ W1 + b1), blocks 0..127 ----------
    if (bid < 128) {
        int b  = bid >> 4;
        int k0 = (bid & 15) * 64;
        int k  = k0 + lane;
        float acc = 0.0f;
        #pragma unroll 8
        for (int ii = 0; ii < 64; ++ii) {
            int i = wid * 64 + ii;
            acc += loc[b * D_IN + i] * W1[i * D_HID + k];
        }
        red[tid] = acc;
        __syncthreads();
        if (wid == 0) {
            float s = red[lane] + red[64 + lane] + red[128 + lane] + red[192 + lane];
            s += b1[k];
            s = (s >= 0.0f) ? s : 0.1f * s;
            __hip_atomic_store(&hT[k * B_ + b], s, __ATOMIC_RELAXED, __HIP_MEMORY_SCOPE_AGENT);
        }
    }
    grid_barrier(flags, gen, 1u);

    // ---------- P2: split-K partial GEMM, 1256 units spread 1/wave over all blocks ----------
    {
        int u = -1;
        if (wid == 0) u = bid;                                   // units 0..1249
        else if (wid == 1 && bid < NUNITS - NBLK) u = NBLK + bid; // units 1250..1255
        if (u >= 0) {
            int jblk = u % 157;
            int ks   = u / 157;
            int j4   = jblk * 64 + lane;
            if (j4 < HW4) {
                int k0 = ks * CHUNK;
                const f32x4* __restrict__ W24 = (const f32x4*)W2;
                f32x4 acc[B_];
                #pragma unroll
                for (int b = 0; b < B_; ++b) acc[b] = (f32x4)0.0f;
                #pragma unroll 8
                for (int kk = 0; kk < CHUNK; ++kk) {
                    int k = k0 + kk;
                    f32x4 wv = __builtin_nontemporal_load(&W24[k * HW4 + j4]);
                    const float* __restrict__ h = &hT[k * B_];   // wave-uniform
                    #pragma unroll
                    for (int b = 0; b < B_; ++b)
                        acc[b] += wv * h[b];
                }
                f32x4* __restrict__ p4 = (f32x4*)partial;
                #pragma unroll
                for (int b = 0; b < B_; ++b)
                    store16_agent(acc[b], &p4[(ks * B_ + b) * HW4 + j4]);
            }
        }
    }
    grid_barrier(flags, gen, 2u);

    // ---------- P3: wmap = 1 + b2 + sum_ks partial ----------
    {
        int t = bid * NTHR + tid;
        if (t < B_ * HW4) {
            int b  = t / HW4;
            int j4 = t - b * HW4;
            const f32x4* __restrict__ p4  = (const f32x4*)partial;
            const f32x4* __restrict__ b24 = (const f32x4*)b2;
            f32x4 s = b24[j4] + 1.0f;
            #pragma unroll
            for (int ks = 0; ks < KS; ++ks)
                s += p4[(ks * B_ + b) * HW4 + j4];
            store16_agent(s, &((f32x4*)wmap)[b * HW4 + j4]);
        }
    }
    grid_barrier(flags, gen, 3u);

    // ---------- P4: out = x * wmap ----------
    // gid stride GSZ=320000 = 32*HW4 -> p invariant; CHW4 = 8*GSZ -> batch index
    // bb = n/8 is the batch dim. 8 b-segments x 8-deep load batches.
    {
        const int gid = bid * NTHR + tid;                 // 0..319999
        const unsigned p = (unsigned)gid % HW4;
        const f32x4* __restrict__ x4 = (const f32x4*)x;
        const f32x4* __restrict__ w4 = (const f32x4*)wmap;
        f32x4* __restrict__ o4 = (f32x4*)out;
        int i = gid;
        #pragma unroll 1
        for (int bb = 0; bb < B_; ++bb) {
            const f32x4 wv = w4[bb * HW4 + p];            // L2-hot (1.28 MB)
            f32x4 xv[8];
            #pragma unroll
            for (int n = 0; n < 8; ++n)
                xv[n] = __builtin_nontemporal_load(&x4[i + n * GSZ]);
            #pragma unroll
            for (int n = 0; n < 8; ++n)
                __builtin_nontemporal_store(xv[n] * wv, &o4[i + n * GSZ]);
            i += 8 * GSZ;
        }
    }
}

extern "C" void kernel_launch(void* const* d_in, const int* in_sizes, int n_in,
                              void* d_out, int out_size, void* d_ws, size_t ws_size,
                              hipStream_t stream) {
    const float* x   = (const float*)d_in[0];
    const float* loc = (const float*)d_in[1];
    const float* W1  = (const float*)d_in[2];
    const float* b1  = (const float*)d_in[3];
    const float* W2  = (const float*)d_in[4];
    const float* b2  = (const float*)d_in[5];
    float* out = (float*)d_out;

    unsigned* gen   = (unsigned*)d_ws;                       // word 0
    unsigned* flags = (unsigned*)((char*)d_ws + 256);        // 1250 words
    float* hT       = (float*)((char*)d_ws + 8192);          // 32 KB
    float* partial  = (float*)((char*)d_ws + 8192 + 32768);  // 10.24 MB (KS=8)
    float* wmap     = (float*)((char*)d_ws + 8192 + 32768
                               + (size_t)KS * B_ * D_OUT * sizeof(float));

    // zero gen+flags every call: deterministic, capture-safe
    hipMemsetAsync(d_ws, 0, 8192, stream);

    fused_kernel<<<NBLK, NTHR, 0, stream>>>(x, loc, W1, b1, W2, b2, out,
                                            gen, flags, hT, partial, wmap);
}

// Round 13
// 410.227 us; speedup vs baseline: 1.3426x; 1.3426x over previous
//
#include <hip/hip_runtime.h>

#define B_    8
#define D_IN  256
#define D_HID 1024
#define D_OUT 40000       // = 200*200
#define HW4   10000       // D_OUT/4
#define CHW4  2560000     // 256*200*200/4
#define KS    8
#define CHUNK 128         // D_HID/KS
#define NUNITS 1256       // 157*KS partial units (one per 64-thr block)
#define RBLK  1250        // reduce blocks: 1250*64 = 80000 items exactly

typedef float f32x4 __attribute__((ext_vector_type(4)));
typedef unsigned long long u64;

// agent-scope 16B store (2x64b atomics): visible at coherence point (R8-proven)
__device__ __forceinline__ void store16_agent(f32x4 v, f32x4* p) {
    union { f32x4 v; u64 q[2]; } u; u.v = v;
    u64* d = (u64*)p;
    __hip_atomic_store(d,     u.q[0], __ATOMIC_RELAXED, __HIP_MEMORY_SCOPE_AGENT);
    __hip_atomic_store(d + 1, u.q[1], __ATOMIC_RELAXED, __HIP_MEMORY_SCOPE_AGENT);
}

// Kernel A: 1256 blocks x 64 threads, one wave each, no LDS, no launch_bounds.
// Phase 0: first 128 ARRIVING blocks (atomic ticket -> already resident, no
//          deadlock) compute mlp1; everyone spins on f128.
// Phase 1: partial GEMM, unit = bid (R10's proven inner loop).
// Phase 2: count-barrier (all 1256 blocks co-resident: 1-wave, 0-LDS blocks,
//          capacity >= 16/CU = 4096 >> 1256), then blocks 0..1249 reduce.
__global__ void mlpA_kernel(const float* __restrict__ loc,
                            const float* __restrict__ W1,
                            const float* __restrict__ b1,
                            const float* __restrict__ W2,
                            const float* __restrict__ b2,
                            unsigned* __restrict__ ctl,
                            float* __restrict__ hT,
                            float* __restrict__ partial,
                            float* __restrict__ wmap) {
    const int bid  = blockIdx.x;
    const int lane = threadIdx.x;          // 64 threads = 1 wave
    unsigned* ticket = ctl;
    unsigned* f128   = ctl + 32;           // separate cachelines
    unsigned* done   = ctl + 64;

    // ---- phase 0: mlp1 on first 128 arrivals ----
    unsigned t;
    if (lane == 0)
        t = __hip_atomic_fetch_add(ticket, 1u, __ATOMIC_RELAXED, __HIP_MEMORY_SCOPE_AGENT);
    t = (unsigned)__shfl((int)t, 0);
    if (t < 128u) {
        int b = (int)(t >> 4);
        int k = (int)(t & 15u) * 64 + lane;
        float acc = 0.0f;
        #pragma unroll 8
        for (int i = 0; i < D_IN; ++i)
            acc += loc[b * D_IN + i] * W1[i * D_HID + k];   // loc uniform; W1 256B coalesced
        acc += b1[k];
        acc = (acc >= 0.0f) ? acc : 0.1f * acc;
        __hip_atomic_store(&hT[k * B_ + b], acc, __ATOMIC_RELAXED, __HIP_MEMORY_SCOPE_AGENT);
        __builtin_amdgcn_fence(__ATOMIC_RELEASE, "agent");
        if (lane == 0)
            __hip_atomic_fetch_add(f128, 1u, __ATOMIC_RELEASE, __HIP_MEMORY_SCOPE_AGENT);
    }
    if (lane == 0)
        while (__hip_atomic_load(f128, __ATOMIC_RELAXED, __HIP_MEMORY_SCOPE_AGENT) < 128u)
            __builtin_amdgcn_s_sleep(4);
    // wave reconverges only after lane0 exits the spin
    __builtin_amdgcn_fence(__ATOMIC_ACQUIRE, "agent");

    // ---- phase 1: split-K partial, unit = bid ----
    {
        int jblk = bid % 157;
        int ks   = bid / 157;
        int j4   = jblk * 64 + lane;
        if (j4 < HW4) {
            int k0 = ks * CHUNK;
            const f32x4* __restrict__ W24 = (const f32x4*)W2;
            f32x4 acc[B_];
            #pragma unroll
            for (int b = 0; b < B_; ++b) acc[b] = (f32x4)0.0f;
            #pragma unroll 8
            for (int kk = 0; kk < CHUNK; ++kk) {
                int k = k0 + kk;
                f32x4 wv = __builtin_nontemporal_load(&W24[k * HW4 + j4]);
                const float* __restrict__ h = &hT[k * B_];   // wave-uniform
                #pragma unroll
                for (int b = 0; b < B_; ++b)
                    acc[b] += wv * h[b];
            }
            f32x4* __restrict__ p4 = (f32x4*)partial;
            #pragma unroll
            for (int b = 0; b < B_; ++b)
                store16_agent(acc[b], &p4[(ks * B_ + b) * HW4 + j4]);
        }
    }
    __builtin_amdgcn_fence(__ATOMIC_RELEASE, "agent");
    if (lane == 0) {
        __hip_atomic_fetch_add(done, 1u, __ATOMIC_RELEASE, __HIP_MEMORY_SCOPE_AGENT);
        while (__hip_atomic_load(done, __ATOMIC_RELAXED, __HIP_MEMORY_SCOPE_AGENT) < NUNITS)
            __builtin_amdgcn_s_sleep(4);
    }
    __builtin_amdgcn_fence(__ATOMIC_ACQUIRE, "agent");

    // ---- phase 2: reduce + bias -> wmap, blocks 0..1249 ----
    if (bid < RBLK) {
        int tt = bid * 64 + lane;          // 0..79999
        int b  = tt / HW4;
        int j4 = tt - b * HW4;
        const f32x4* __restrict__ p4  = (const f32x4*)partial;
        f32x4 s = ((const f32x4*)b2)[j4] + 1.0f;
        #pragma unroll
        for (int ks = 0; ks < KS; ++ks)
            s += p4[(ks * B_ + b) * HW4 + j4];
        ((f32x4*)wmap)[b * HW4 + j4] = s;  // kernel-end flush publishes to kernel B
    }
}

// Kernel B: R10's proven scale, untouched. Grid (625,8): per-batch stride
// 160000 vec4 = 16*HW4 -> p invariant per thread; wv hoisted; nt load+store.
__global__ void scale_kernel(const float* __restrict__ x,
                             const float* __restrict__ wmap,
                             float* __restrict__ out) {
    const int b = blockIdx.y;
    const int g = blockIdx.x * 256 + threadIdx.x;        // 0..159999
    const unsigned p = (unsigned)g % HW4;                // invariant across iters

    const f32x4* __restrict__ x4 = (const f32x4*)x + (size_t)b * CHW4;
    f32x4* __restrict__ o4       = (f32x4*)out + (size_t)b * CHW4;
    const f32x4 wv = ((const f32x4*)wmap)[(size_t)b * HW4 + p];  // one load, hoisted

    #pragma unroll 4
    for (int n = 0; n < 16; ++n) {
        int i = g + n * 160000;
        f32x4 xv = __builtin_nontemporal_load(&x4[i]);
        __builtin_nontemporal_store(xv * wv, &o4[i]);
    }
}

extern "C" void kernel_launch(void* const* d_in, const int* in_sizes, int n_in,
                              void* d_out, int out_size, void* d_ws, size_t ws_size,
                              hipStream_t stream) {
    const float* x   = (const float*)d_in[0];
    const float* loc = (const float*)d_in[1];
    const float* W1  = (const float*)d_in[2];
    const float* b1  = (const float*)d_in[3];
    const float* W2  = (const float*)d_in[4];
    const float* b2  = (const float*)d_in[5];
    float* out = (float*)d_out;

    unsigned* ctl  = (unsigned*)d_ws;                        // 512 B control
    float* hT      = (float*)((char*)d_ws + 512);            // 32 KB
    float* partial = (float*)((char*)d_ws + 512 + 32768);    // 10.24 MB
    float* wmap    = (float*)((char*)d_ws + 512 + 32768
                              + (size_t)KS * B_ * D_OUT * sizeof(float)); // 1.28 MB

    // zero ticket/flag/done every call: deterministic, capture-safe
    hipMemsetAsync(d_ws, 0, 512, stream);

    mlpA_kernel<<<NUNITS, 64, 0, stream>>>(loc, W1, b1, W2, b2, ctl, hT, partial, wmap);
    scale_kernel<<<dim3(625, 8), 256, 0, stream>>>(x, wmap, out);
}

// Round 14
// 162.194 us; speedup vs baseline: 3.3959x; 2.5292x over previous
//
#include <hip/hip_runtime.h>

#define B_    8
#define D_IN  256
#define D_HID 1024
#define D_OUT 40000       // = 200*200
#define HW4   10000       // D_OUT/4
#define CHW4  2560000     // 256*200*200/4

typedef float f32x4 __attribute__((ext_vector_type(4)));

// Kernel 1: hT[k*8+b] = leakyrelu(loc[b,:] @ W1[:,k] + b1[k])
// 128 blocks x 256 thr; wave w covers 64 i's; LDS reduce across 4 waves.
__global__ void mlp1_kernel(const float* __restrict__ loc,
                            const float* __restrict__ W1,
                            const float* __restrict__ b1,
                            float* __restrict__ hT) {
    __shared__ float red[256];
    int g    = blockIdx.x;
    int b    = g >> 4;
    int k0   = (g & 15) * 64;
    int w    = threadIdx.x >> 6;
    int lane = threadIdx.x & 63;
    int k    = k0 + lane;

    float acc = 0.0f;
    #pragma unroll 8
    for (int ii = 0; ii < 64; ++ii) {
        int i = w * 64 + ii;
        acc += loc[b * D_IN + i] * W1[i * D_HID + k];
    }
    red[threadIdx.x] = acc;
    __syncthreads();
    if (w == 0) {
        float s = red[lane] + red[64 + lane] + red[128 + lane] + red[192 + lane];
        s += b1[k];
        s = (s >= 0.0f) ? s : 0.1f * s;
        hT[k * B_ + b] = s;
    }
}

// Kernel 2a: split-K partial, float4 over columns, 1-wave blocks, grid (157,KS).
template<int KS>
__global__ void mlp2_partial_kernel(const float* __restrict__ hT,
                                    const float* __restrict__ W2,
                                    float* __restrict__ partial) {
    constexpr int CHUNK = D_HID / KS;
    int j4 = blockIdx.x * 64 + threadIdx.x;
    if (j4 >= HW4) return;
    int ks = blockIdx.y;
    int k0 = ks * CHUNK;
    const f32x4* __restrict__ W24 = (const f32x4*)W2;
    f32x4 acc[B_];
    #pragma unroll
    for (int b = 0; b < B_; ++b) acc[b] = (f32x4)0.0f;
    #pragma unroll 8
    for (int kk = 0; kk < CHUNK; ++kk) {
        int k = k0 + kk;
        f32x4 wv = __builtin_nontemporal_load(&W24[k * HW4 + j4]); // read-once stream
        const float* __restrict__ h = &hT[k * B_];                 // wave-uniform, L2-hit
        #pragma unroll
        for (int b = 0; b < B_; ++b)
            acc[b] += wv * h[b];
    }
    f32x4* __restrict__ p4 = (f32x4*)partial;
    #pragma unroll
    for (int b = 0; b < B_; ++b)
        __builtin_nontemporal_store(acc[b], &p4[(ks * B_ + b) * HW4 + j4]);
}

// Kernel 2b: reduce partials + bias, write 1+w. KS unrolled, loads independent.
template<int KS>
__global__ void mlp2_reduce_kernel(const float* __restrict__ partial,
                                   const float* __restrict__ b2,
                                   float* __restrict__ wmap) {
    int t = blockIdx.x * blockDim.x + threadIdx.x;   // over 80000
    if (t >= B_ * HW4) return;
    int b = t / HW4;
    int j4 = t - b * HW4;
    const f32x4* __restrict__ p4  = (const f32x4*)partial;
    const f32x4* __restrict__ b24 = (const f32x4*)b2;
    f32x4 s = b24[j4] + 1.0f;
    #pragma unroll
    for (int ks = 0; ks < KS; ++ks)
        s += __builtin_nontemporal_load(&p4[(ks * B_ + b) * HW4 + j4]);
    ((f32x4*)wmap)[b * HW4 + j4] = s;     // cached: scale reads it next
}

// Kernel 3: out = x * (1+w). Grid (625, 8): blockIdx.y = batch; per-batch stride
// 625*256 = 160000 vec4 = 16*HW4, so each thread's spatial index p is INVARIANT
// across its 16 iterations: wv loaded once, loop body = load/mul/store only.
__global__ void scale_kernel(const float* __restrict__ x,
                             const float* __restrict__ wmap,
                             float* __restrict__ out) {
    const int b = blockIdx.y;
    const int g = blockIdx.x * 256 + threadIdx.x;        // 0..159999
    const unsigned p = (unsigned)g % HW4;                // invariant across iters

    const f32x4* __restrict__ x4 = (const f32x4*)x + (size_t)b * CHW4;
    f32x4* __restrict__ o4       = (f32x4*)out + (size_t)b * CHW4;
    const f32x4 wv = ((const f32x4*)wmap)[(size_t)b * HW4 + p];  // one load, hoisted

    #pragma unroll 4
    for (int n = 0; n < 16; ++n) {
        int i = g + n * 160000;
        f32x4 xv = __builtin_nontemporal_load(&x4[i]);
        __builtin_nontemporal_store(xv * wv, &o4[i]);
    }
}

template<int KS>
static void launch_mlp2(const float* hT, const float* W2, const float* b2,
                        float* partial, float* wmap, hipStream_t stream) {
    dim3 g2(157, KS);
    mlp2_partial_kernel<KS><<<g2, 64, 0, stream>>>(hT, W2, partial);
    mlp2_reduce_kernel<KS><<<(B_ * HW4 + 255) / 256, 256, 0, stream>>>(partial, b2, wmap);
}

extern "C" void kernel_launch(void* const* d_in, const int* in_sizes, int n_in,
                              void* d_out, int out_size, void* d_ws, size_t ws_size,
                              hipStream_t stream) {
    const float* x   = (const float*)d_in[0];
    const float* loc = (const float*)d_in[1];
    const float* W1  = (const float*)d_in[2];
    const float* b1  = (const float*)d_in[3];
    const float* W2  = (const float*)d_in[4];
    const float* b2  = (const float*)d_in[5];
    float* out = (float*)d_out;

    float* hT      = (float*)d_ws;                       // 32 KB
    float* partial = (float*)((char*)d_ws + 32768);

    size_t base = 32768;
    int KS = 1;
    for (int cand = 8; cand >= 1; cand >>= 1) {
        size_t need = base + (size_t)(cand + 1) * B_ * D_OUT * sizeof(float);
        if (need <= ws_size) { KS = cand; break; }
    }
    float* wmap = (float*)((char*)d_ws + base
                           + (size_t)KS * B_ * D_OUT * sizeof(float));

    mlp1_kernel<<<128, 256, 0, stream>>>(loc, W1, b1, hT);

    switch (KS) {
        case 8:  launch_mlp2<8>(hT, W2, b2, partial, wmap, stream); break;
        case 4:  launch_mlp2<4>(hT, W2, b2, partial, wmap, stream); break;
        case 2:  launch_mlp2<2>(hT, W2, b2, partial, wmap, stream); break;
        default: launch_mlp2<1>(hT, W2, b2, partial, wmap, stream); break;
    }

    scale_kernel<<<dim3(625, 8), 256, 0, stream>>>(x, wmap, out);
}